// Round 14
// baseline (717.162 us; speedup 1.0000x reference)
//
#include <hip/hip_runtime.h>

#define D 64
#define NPB 64      // nodes per block in layer kernel
#define RS 68       // padded LDS row stride (floats)
#define EPSV 1e-5f
#define SLOPE 0.01f
#define R1B 64      // blocks in stage-1 stats reduce

__device__ __forceinline__ float lrelu(float v) { return v > 0.f ? v : SLOPE * v; }

// ---------------- CSR build ----------------

__global__ void count_kernel(const int* __restrict__ dst, int E, int* __restrict__ cnt) {
    int i = blockIdx.x * 256 + threadIdx.x;
    if (i < E) atomicAdd(&cnt[dst[i]], 1);
}

__global__ void scan1_kernel(const int* __restrict__ cnt, int N, int* __restrict__ psum) {
    __shared__ int sd[256];
    int t = threadIdx.x;
    int i = blockIdx.x * 256 + t;
    sd[t] = (i < N) ? cnt[i] : 0;
    __syncthreads();
    for (int o = 128; o > 0; o >>= 1) {
        if (t < o) sd[t] += sd[t + o];
        __syncthreads();
    }
    if (t == 0) psum[blockIdx.x] = sd[0];
}

__global__ void scan2_kernel(int* __restrict__ psum, int nb) {
    __shared__ int sd[1024];
    int t = threadIdx.x;
    int v = (t < nb) ? psum[t] : 0;
    int x = v;
    sd[t] = x;
    __syncthreads();
    for (int o = 1; o < 1024; o <<= 1) {
        int y = (t >= o) ? sd[t - o] : 0;
        __syncthreads();
        x += y;
        sd[t] = x;
        __syncthreads();
    }
    if (t < nb) psum[t] = x - v;  // exclusive
}

__global__ void scan3_kernel(const int* __restrict__ cnt, const int* __restrict__ psum,
                             int N, int E, int* __restrict__ offsets) {
    __shared__ int sd[256];
    int t = threadIdx.x;
    int i = blockIdx.x * 256 + t;
    int v = (i < N) ? cnt[i] : 0;
    int x = v;
    sd[t] = x;
    __syncthreads();
    for (int o = 1; o < 256; o <<= 1) {
        int y = (t >= o) ? sd[t - o] : 0;
        __syncthreads();
        x += y;
        sd[t] = x;
        __syncthreads();
    }
    if (i < N) offsets[i] = psum[blockIdx.x] + x - v;  // exclusive global
    if (i == 0) offsets[N] = E;
}

__global__ void fill_kernel(const int* __restrict__ src, const int* __restrict__ dst, int E,
                            const int* __restrict__ offsets, int* __restrict__ cursor,
                            int* __restrict__ col) {
    int i = blockIdx.x * 256 + threadIdx.x;
    if (i < E) {
        int d = dst[i];
        int p = atomicAdd(&cursor[d], 1);
        col[offsets[d] + p] = src[i];
    }
}

// ---------------- BN stats two-stage parallel reduce ----------------

__global__ void reduce1_kernel(const float* __restrict__ blkstats, int B,
                               float* __restrict__ partial) {
    __shared__ float4 sd[256];
    const int t    = threadIdx.x;
    const int c4   = t & 31;   // float4 column (32 x 4 = 128 floats)
    const int rg   = t >> 5;   // rowgroup 0..7
    float4 acc = make_float4(0.f, 0.f, 0.f, 0.f);
    for (int i = blockIdx.x * 8 + rg; i < B; i += R1B * 8) {
        float4 v = *(const float4*)&blkstats[(size_t)i * 128 + c4 * 4];
        acc.x += v.x; acc.y += v.y; acc.z += v.z; acc.w += v.w;
    }
    sd[t] = acc;
    __syncthreads();
    #pragma unroll
    for (int o = 4; o > 0; o >>= 1) {
        if (rg < o) {
            float4 a = sd[rg * 32 + c4];
            float4 b = sd[(rg + o) * 32 + c4];
            a.x += b.x; a.y += b.y; a.z += b.z; a.w += b.w;
            sd[rg * 32 + c4] = a;
        }
        __syncthreads();
    }
    if (t < 32)
        *(float4*)&partial[(size_t)blockIdx.x * 128 + c4 * 4] = sd[c4];
}

__global__ void reduce2_affine_kernel(const float* __restrict__ partial,
                                      const float* __restrict__ g, const float* __restrict__ b,
                                      float* __restrict__ a, float* __restrict__ c, float invN) {
    __shared__ float sd[2][128];
    const int t    = threadIdx.x;   // 256
    const int f    = t & 127;
    const int half = t >> 7;
    float s = 0.f;
    for (int i = half; i < R1B; i += 2)
        s += partial[(size_t)i * 128 + f];
    sd[half][f] = s;
    __syncthreads();
    if (t < 64) {
        float su = sd[0][t]      + sd[1][t];
        float sq = sd[0][64 + t] + sd[1][64 + t];
        float mu  = su * invN;
        float var = sq * invN - mu * mu;
        float aj  = g[t] * rsqrtf(var + EPSV);
        a[t] = aj;
        c[t] = b[t] - mu * aj;
    }
}

// ---------------- gather-mean kernel: one wave per node ----------------

template <int AFF>
__global__ __launch_bounds__(256, 8)
void agg_kernel(const float* __restrict__ in,
                const int* __restrict__ offsets,
                const int* __restrict__ col,
                const float* __restrict__ aff_a,
                const float* __restrict__ aff_c,
                float* __restrict__ aggout,
                int N)
{
    const int node = blockIdx.x * 4 + (threadIdx.x >> 6);
    const int lane = threadIdx.x & 63;
    if (node >= N) return;

    const int beg = offsets[node];
    const int end = offsets[node + 1];
    const int deg = end - beg;

    float a0 = 0.f, a1 = 0.f, a2 = 0.f, a3 = 0.f;
    float a4 = 0.f, a5 = 0.f, a6 = 0.f, a7 = 0.f;

    for (int cb = beg; cb < end; cb += 64) {
        const int nn = min(64, end - cb);
        const int cidx = (lane < nn) ? col[cb + lane] : 0;
        int j = 0;
        for (; j + 8 <= nn; j += 8) {
            const int c0 = __shfl(cidx, j + 0);
            const int c1 = __shfl(cidx, j + 1);
            const int c2 = __shfl(cidx, j + 2);
            const int c3 = __shfl(cidx, j + 3);
            const int c4 = __shfl(cidx, j + 4);
            const int c5 = __shfl(cidx, j + 5);
            const int c6 = __shfl(cidx, j + 6);
            const int c7 = __shfl(cidx, j + 7);
            a0 += in[(size_t)c0 * D + lane];
            a1 += in[(size_t)c1 * D + lane];
            a2 += in[(size_t)c2 * D + lane];
            a3 += in[(size_t)c3 * D + lane];
            a4 += in[(size_t)c4 * D + lane];
            a5 += in[(size_t)c5 * D + lane];
            a6 += in[(size_t)c6 * D + lane];
            a7 += in[(size_t)c7 * D + lane];
        }
        for (; j + 4 <= nn; j += 4) {
            const int c0 = __shfl(cidx, j + 0);
            const int c1 = __shfl(cidx, j + 1);
            const int c2 = __shfl(cidx, j + 2);
            const int c3 = __shfl(cidx, j + 3);
            a0 += in[(size_t)c0 * D + lane];
            a1 += in[(size_t)c1 * D + lane];
            a2 += in[(size_t)c2 * D + lane];
            a3 += in[(size_t)c3 * D + lane];
        }
        for (; j < nn; ++j) {
            const int c = __shfl(cidx, j);
            a0 += in[(size_t)c * D + lane];
        }
    }

    float agg = 0.f;
    if (deg > 0) {
        agg = (((a0 + a1) + (a2 + a3)) + ((a4 + a5) + (a6 + a7))) / (float)deg;
        if (AFF) agg = agg * aff_a[lane] + aff_c[lane];
    }
    aggout[(size_t)node * D + lane] = agg;
}

// ---------------- fused dense layer ----------------
// Round-14 change: weights are NOT staged to LDS. Inner-loop weight reads are
// wave-uniform addresses -> scalar/L1-broadcast loads. LDS drops 66->34.8 KB,
// occupancy 2->4 blocks/CU, and the weight-staging phase disappears (round-13
// layer_kernel was ~65us vs ~15us roofline: latency-bound at 8 waves/CU).

template <int MODE>
__global__ __launch_bounds__(256, 4)
void layer_kernel(const float* __restrict__ in,
                  const float* __restrict__ agg,
                  const float* __restrict__ aff_a,
                  const float* __restrict__ aff_c,
                  const float* __restrict__ Wl,
                  const float* __restrict__ bl,
                  const float* __restrict__ Wr,
                  float* __restrict__ hout,
                  float* __restrict__ blkstats,
                  const float* __restrict__ wfc,
                  const float* __restrict__ bfc,
                  float* __restrict__ out,
                  int N)
{
    __shared__ float aggs[NPB * RS];
    __shared__ float xs[NPB * RS];

    const int tid  = threadIdx.x;
    const int base = blockIdx.x * NPB;
    const int wave = tid >> 6;
    const int lane = tid & 63;

    // stage agg rows + self rows (+input affine on self)
    {
        const int r0 = tid >> 4;          // 0..15
        const int c4 = (tid & 15) * 4;    // 0..60
        #pragma unroll
        for (int pp = 0; pp < 4; ++pp) {
            int row = pp * 16 + r0;
            int gn  = base + row;
            float4 va = make_float4(0.f, 0.f, 0.f, 0.f);
            float4 vx = make_float4(0.f, 0.f, 0.f, 0.f);
            if (gn < N) {
                va = *(const float4*)&agg[(size_t)gn * D + c4];
                vx = *(const float4*)&in[(size_t)gn * D + c4];
            }
            if (MODE != 0) {
                vx.x = vx.x * aff_a[c4 + 0] + aff_c[c4 + 0];
                vx.y = vx.y * aff_a[c4 + 1] + aff_c[c4 + 1];
                vx.z = vx.z * aff_a[c4 + 2] + aff_c[c4 + 2];
                vx.w = vx.w * aff_a[c4 + 3] + aff_c[c4 + 3];
            }
            *(float4*)&aggs[row * RS + c4] = va;
            *(float4*)&xs[row * RS + c4]   = vx;
        }
    }
    __syncthreads();

    // matmul: wave w computes features [w*16, w*16+16) for all 64 nodes; lane = node
    float acc[16];
    #pragma unroll
    for (int jj = 0; jj < 16; ++jj) acc[jj] = 0.f;
    const int jg = wave * 16;
    const int n  = lane;
    for (int k = 0; k < D; k += 4) {
        float4 a4 = *(const float4*)&aggs[n * RS + k];
        float4 x4 = *(const float4*)&xs[n * RS + k];
        const float* ap = (const float*)&a4;
        const float* xp = (const float*)&x4;
        #pragma unroll
        for (int kk = 0; kk < 4; ++kk) {
            const float avv = ap[kk];
            const float xvv = xp[kk];
            const float4* wl4p = (const float4*)&Wl[(size_t)(k + kk) * D + jg];
            const float4* wr4p = (const float4*)&Wr[(size_t)(k + kk) * D + jg];
            #pragma unroll
            for (int q = 0; q < 4; ++q) {
                float4 wl = wl4p[q];
                float4 wr = wr4p[q];
                acc[q * 4 + 0] += avv * wl.x;
                acc[q * 4 + 0] += xvv * wr.x;
                acc[q * 4 + 1] += avv * wl.y;
                acc[q * 4 + 1] += xvv * wr.y;
                acc[q * 4 + 2] += avv * wl.z;
                acc[q * 4 + 2] += xvv * wr.z;
                acc[q * 4 + 3] += avv * wl.w;
                acc[q * 4 + 3] += xvv * wr.w;
            }
        }
    }
    __syncthreads();  // all waves done reading aggs/xs

    if (MODE != 2) {
        float hv[16];
        #pragma unroll
        for (int jj = 0; jj < 16; ++jj) {
            float v = acc[jj] + bl[jg + jj];
            hv[jj] = lrelu(v);
        }
        // transpose through LDS (reuse aggs) for coalesced writeback
        #pragma unroll
        for (int q = 0; q < 4; ++q) {
            float4 v4 = make_float4(hv[q * 4 + 0], hv[q * 4 + 1], hv[q * 4 + 2], hv[q * 4 + 3]);
            *(float4*)&aggs[n * RS + jg + q * 4] = v4;
        }
        __syncthreads();
        {
            const int r0 = tid >> 4;
            const int c4 = (tid & 15) * 4;
            #pragma unroll
            for (int pp = 0; pp < 4; ++pp) {
                int row = pp * 16 + r0;
                int gn  = base + row;
                if (gn < N)
                    *(float4*)&hout[(size_t)gn * D + c4] = *(const float4*)&aggs[row * RS + c4];
            }
        }
        // BN partial stats: per-wave shuffle reduce, non-atomic per-block store
        bool valid = (base + n) < N;
        #pragma unroll
        for (int jj = 0; jj < 16; ++jj) {
            float s1 = valid ? hv[jj] : 0.f;
            float s2 = s1 * s1;
            #pragma unroll
            for (int o = 32; o > 0; o >>= 1) {
                s1 += __shfl_xor(s1, o, 64);
                s2 += __shfl_xor(s2, o, 64);
            }
            if (lane == 0) {
                blkstats[(size_t)blockIdx.x * 128 + jg + jj]      = s1;
                blkstats[(size_t)blockIdx.x * 128 + 64 + jg + jj] = s2;
            }
        }
    } else {
        // fused FC head: out[n] = lrelu(h2) . wfc + bfc
        float s = 0.f;
        #pragma unroll
        for (int jj = 0; jj < 16; ++jj) {
            float v = acc[jj] + bl[jg + jj];
            s += lrelu(v) * wfc[jg + jj];
        }
        aggs[wave * 64 + n] = s;   // scratch reuse, post-barrier
        __syncthreads();
        if (wave == 0) {
            int gn = base + lane;
            if (gn < N)
                out[gn] = aggs[lane] + aggs[64 + lane] + aggs[128 + lane] + aggs[192 + lane] + bfc[0];
        }
    }
}

// ---------------- launch ----------------

extern "C" void kernel_launch(void* const* d_in, const int* in_sizes, int n_in,
                              void* d_out, int out_size, void* d_ws, size_t ws_size,
                              hipStream_t stream) {
    const float* x   = (const float*)d_in[0];
    const int*   ei  = (const int*)d_in[1];
    const float* W0l = (const float*)d_in[2];
    const float* b0  = (const float*)d_in[3];
    const float* W0r = (const float*)d_in[4];
    const float* g0  = (const float*)d_in[5];
    const float* be0 = (const float*)d_in[6];
    const float* W1l = (const float*)d_in[7];
    const float* b1  = (const float*)d_in[8];
    const float* W1r = (const float*)d_in[9];
    const float* g1  = (const float*)d_in[10];
    const float* be1 = (const float*)d_in[11];
    const float* W2l = (const float*)d_in[12];
    const float* b2  = (const float*)d_in[13];
    const float* W2r = (const float*)d_in[14];
    const float* Wfc = (const float*)d_in[15];
    const float* bfc = (const float*)d_in[16];
    float* out = (float*)d_out;

    const int N = in_sizes[0] / D;
    const int E = in_sizes[1] / 2;
    const int* src = ei;
    const int* dst = ei + E;

    const int lbl = (N + NPB - 1) / NPB;

    char* p = (char*)d_ws;
    auto carve = [&](size_t bytes) {
        char* r = p;
        p += (bytes + 255) & ~(size_t)255;
        return r;
    };
    int*   cnt      = (int*)carve((size_t)2 * N * 4);     // cnt + cursor contiguous
    int*   cursor   = cnt + N;
    int*   offsets  = (int*)carve((size_t)(N + 1) * 4);
    int*   psum     = (int*)carve(1024 * 4);
    int*   col      = (int*)carve((size_t)E * 4);
    float* blkstats = (float*)carve((size_t)lbl * 128 * 4);
    float* partial  = (float*)carve((size_t)R1B * 128 * 4);
    float* aff      = (float*)carve(256 * 4);             // a0,c0,a1,c1
    float* h0       = (float*)carve((size_t)N * D * 4);
    float* h1       = (float*)carve((size_t)N * D * 4);
    float* aggbuf   = (float*)carve((size_t)N * D * 4);

    hipMemsetAsync(cnt, 0, (size_t)2 * N * 4, stream);

    const int ebl = (E + 255) / 256;
    const int nbl = (N + 255) / 256;

    count_kernel<<<ebl, 256, 0, stream>>>(dst, E, cnt);
    scan1_kernel<<<nbl, 256, 0, stream>>>(cnt, N, psum);
    scan2_kernel<<<1, 1024, 0, stream>>>(psum, nbl);
    scan3_kernel<<<nbl, 256, 0, stream>>>(cnt, psum, N, E, offsets);
    fill_kernel<<<ebl, 256, 0, stream>>>(src, dst, E, offsets, cursor, col);

    const int abl = (N + 3) / 4;          // 4 nodes (waves) per block
    const float invN = 1.f / (float)N;

    // layer 0
    agg_kernel<0><<<abl, 256, 0, stream>>>(x, offsets, col, nullptr, nullptr, aggbuf, N);
    layer_kernel<0><<<lbl, 256, 0, stream>>>(x, aggbuf, nullptr, nullptr,
                                             W0l, b0, W0r, h0, blkstats,
                                             nullptr, nullptr, nullptr, N);
    reduce1_kernel<<<R1B, 256, 0, stream>>>(blkstats, lbl, partial);
    reduce2_affine_kernel<<<1, 256, 0, stream>>>(partial, g0, be0, aff + 0, aff + 64, invN);
    // layer 1
    agg_kernel<1><<<abl, 256, 0, stream>>>(h0, offsets, col, aff + 0, aff + 64, aggbuf, N);
    layer_kernel<1><<<lbl, 256, 0, stream>>>(h0, aggbuf, aff + 0, aff + 64,
                                             W1l, b1, W1r, h1, blkstats,
                                             nullptr, nullptr, nullptr, N);
    reduce1_kernel<<<R1B, 256, 0, stream>>>(blkstats, lbl, partial);
    reduce2_affine_kernel<<<1, 256, 0, stream>>>(partial, g1, be1, aff + 128, aff + 192, invN);
    // layer 2 + FC head
    agg_kernel<1><<<abl, 256, 0, stream>>>(h1, offsets, col, aff + 128, aff + 192, aggbuf, N);
    layer_kernel<2><<<lbl, 256, 0, stream>>>(h1, aggbuf, aff + 128, aff + 192,
                                             W2l, b2, W2r, nullptr, nullptr,
                                             Wfc, bfc, out, N);
}

// Round 15
// 544.810 us; speedup vs baseline: 1.3164x; 1.3164x over previous
//
#include <hip/hip_runtime.h>

#define D 64
#define NPB 64      // nodes per block in layer kernel
#define RS 68       // padded LDS row stride (floats)
#define EPSV 1e-5f
#define SLOPE 0.01f
#define R1B 64      // blocks in stage-1 stats reduce

__device__ __forceinline__ float lrelu(float v) { return v > 0.f ? v : SLOPE * v; }

// ---------------- CSR build ----------------

__global__ void count_kernel(const int* __restrict__ dst, int E, int* __restrict__ cnt) {
    int i = blockIdx.x * 256 + threadIdx.x;
    if (i < E) atomicAdd(&cnt[dst[i]], 1);
}

__global__ void scan1_kernel(const int* __restrict__ cnt, int N, int* __restrict__ psum) {
    __shared__ int sd[256];
    int t = threadIdx.x;
    int i = blockIdx.x * 256 + t;
    sd[t] = (i < N) ? cnt[i] : 0;
    __syncthreads();
    for (int o = 128; o > 0; o >>= 1) {
        if (t < o) sd[t] += sd[t + o];
        __syncthreads();
    }
    if (t == 0) psum[blockIdx.x] = sd[0];
}

__global__ void scan2_kernel(int* __restrict__ psum, int nb) {
    __shared__ int sd[1024];
    int t = threadIdx.x;
    int v = (t < nb) ? psum[t] : 0;
    int x = v;
    sd[t] = x;
    __syncthreads();
    for (int o = 1; o < 1024; o <<= 1) {
        int y = (t >= o) ? sd[t - o] : 0;
        __syncthreads();
        x += y;
        sd[t] = x;
        __syncthreads();
    }
    if (t < nb) psum[t] = x - v;  // exclusive
}

__global__ void scan3_kernel(const int* __restrict__ cnt, const int* __restrict__ psum,
                             int N, int E, int* __restrict__ offsets) {
    __shared__ int sd[256];
    int t = threadIdx.x;
    int i = blockIdx.x * 256 + t;
    int v = (i < N) ? cnt[i] : 0;
    int x = v;
    sd[t] = x;
    __syncthreads();
    for (int o = 1; o < 256; o <<= 1) {
        int y = (t >= o) ? sd[t - o] : 0;
        __syncthreads();
        x += y;
        sd[t] = x;
        __syncthreads();
    }
    if (i < N) offsets[i] = psum[blockIdx.x] + x - v;  // exclusive global
    if (i == 0) offsets[N] = E;
}

__global__ void fill_kernel(const int* __restrict__ src, const int* __restrict__ dst, int E,
                            const int* __restrict__ offsets, int* __restrict__ cursor,
                            int* __restrict__ col) {
    int i = blockIdx.x * 256 + threadIdx.x;
    if (i < E) {
        int d = dst[i];
        int p = atomicAdd(&cursor[d], 1);
        col[offsets[d] + p] = src[i];
    }
}

// ---------------- BN stats two-stage parallel reduce ----------------

__global__ void reduce1_kernel(const float* __restrict__ blkstats, int B,
                               float* __restrict__ partial) {
    __shared__ float4 sd[256];
    const int t    = threadIdx.x;
    const int c4   = t & 31;   // float4 column (32 x 4 = 128 floats)
    const int rg   = t >> 5;   // rowgroup 0..7
    float4 acc = make_float4(0.f, 0.f, 0.f, 0.f);
    for (int i = blockIdx.x * 8 + rg; i < B; i += R1B * 8) {
        float4 v = *(const float4*)&blkstats[(size_t)i * 128 + c4 * 4];
        acc.x += v.x; acc.y += v.y; acc.z += v.z; acc.w += v.w;
    }
    sd[t] = acc;
    __syncthreads();
    #pragma unroll
    for (int o = 4; o > 0; o >>= 1) {
        if (rg < o) {
            float4 a = sd[rg * 32 + c4];
            float4 b = sd[(rg + o) * 32 + c4];
            a.x += b.x; a.y += b.y; a.z += b.z; a.w += b.w;
            sd[rg * 32 + c4] = a;
        }
        __syncthreads();
    }
    if (t < 32)
        *(float4*)&partial[(size_t)blockIdx.x * 128 + c4 * 4] = sd[c4];
}

__global__ void reduce2_affine_kernel(const float* __restrict__ partial,
                                      const float* __restrict__ g, const float* __restrict__ b,
                                      float* __restrict__ a, float* __restrict__ c, float invN) {
    __shared__ float sd[2][128];
    const int t    = threadIdx.x;   // 256
    const int f    = t & 127;
    const int half = t >> 7;
    float s = 0.f;
    for (int i = half; i < R1B; i += 2)
        s += partial[(size_t)i * 128 + f];
    sd[half][f] = s;
    __syncthreads();
    if (t < 64) {
        float su = sd[0][t]      + sd[1][t];
        float sq = sd[0][64 + t] + sd[1][64 + t];
        float mu  = su * invN;
        float var = sq * invN - mu * mu;
        float aj  = g[t] * rsqrtf(var + EPSV);
        a[t] = aj;
        c[t] = b[t] - mu * aj;
    }
}

// ---------------- gather-mean kernel: one wave per node ----------------

template <int AFF>
__global__ __launch_bounds__(256, 8)
void agg_kernel(const float* __restrict__ in,
                const int* __restrict__ offsets,
                const int* __restrict__ col,
                const float* __restrict__ aff_a,
                const float* __restrict__ aff_c,
                float* __restrict__ aggout,
                int N)
{
    const int node = blockIdx.x * 4 + (threadIdx.x >> 6);
    const int lane = threadIdx.x & 63;
    if (node >= N) return;

    const int beg = offsets[node];
    const int end = offsets[node + 1];
    const int deg = end - beg;

    float a0 = 0.f, a1 = 0.f, a2 = 0.f, a3 = 0.f;
    float a4 = 0.f, a5 = 0.f, a6 = 0.f, a7 = 0.f;

    for (int cb = beg; cb < end; cb += 64) {
        const int nn = min(64, end - cb);
        const int cidx = (lane < nn) ? col[cb + lane] : 0;
        int j = 0;
        for (; j + 8 <= nn; j += 8) {
            const int c0 = __shfl(cidx, j + 0);
            const int c1 = __shfl(cidx, j + 1);
            const int c2 = __shfl(cidx, j + 2);
            const int c3 = __shfl(cidx, j + 3);
            const int c4 = __shfl(cidx, j + 4);
            const int c5 = __shfl(cidx, j + 5);
            const int c6 = __shfl(cidx, j + 6);
            const int c7 = __shfl(cidx, j + 7);
            a0 += in[(size_t)c0 * D + lane];
            a1 += in[(size_t)c1 * D + lane];
            a2 += in[(size_t)c2 * D + lane];
            a3 += in[(size_t)c3 * D + lane];
            a4 += in[(size_t)c4 * D + lane];
            a5 += in[(size_t)c5 * D + lane];
            a6 += in[(size_t)c6 * D + lane];
            a7 += in[(size_t)c7 * D + lane];
        }
        for (; j + 4 <= nn; j += 4) {
            const int c0 = __shfl(cidx, j + 0);
            const int c1 = __shfl(cidx, j + 1);
            const int c2 = __shfl(cidx, j + 2);
            const int c3 = __shfl(cidx, j + 3);
            a0 += in[(size_t)c0 * D + lane];
            a1 += in[(size_t)c1 * D + lane];
            a2 += in[(size_t)c2 * D + lane];
            a3 += in[(size_t)c3 * D + lane];
        }
        for (; j < nn; ++j) {
            const int c = __shfl(cidx, j);
            a0 += in[(size_t)c * D + lane];
        }
    }

    float agg = 0.f;
    if (deg > 0) {
        agg = (((a0 + a1) + (a2 + a3)) + ((a4 + a5) + (a6 + a7))) / (float)deg;
        if (AFF) agg = agg * aff_a[lane] + aff_c[lane];
    }
    aggout[(size_t)node * D + lane] = agg;
}

// ---------------- fused dense layer ----------------
// WSTYLE 0: weights staged in LDS (round-13 proven path; 66.8KB LDS, 2 blk/CU,
//           LDS-BW-bound on weight re-reads ~65us).
// WSTYLE 1: weights read from global at readfirstlane-forced UNIFORM addresses
//           -> s_load through scalar cache, no LDS staging, 34.8KB LDS,
//           4 blk/CU. (Round-14's version without readfirstlane compiled to
//           per-lane vector loads: 123us. Divergence analysis can't prove
//           tid>>6 uniform; readfirstlane can.)
// This round runs an in-situ A/B: layer<0,0>, layer<1,1>, layer<2,0>.

template <int MODE, int WSTYLE>
__global__ __launch_bounds__(256, WSTYLE ? 4 : 2)
void layer_kernel(const float* __restrict__ in,
                  const float* __restrict__ agg,
                  const float* __restrict__ aff_a,
                  const float* __restrict__ aff_c,
                  const float* __restrict__ Wl,
                  const float* __restrict__ bl,
                  const float* __restrict__ Wr,
                  float* __restrict__ hout,
                  float* __restrict__ blkstats,
                  const float* __restrict__ wfc,
                  const float* __restrict__ bfc,
                  float* __restrict__ out,
                  int N)
{
    __shared__ float WlS[WSTYLE == 0 ? D * D : 4];
    __shared__ float WrS[WSTYLE == 0 ? D * D : 4];
    __shared__ float aggs[NPB * RS];
    __shared__ float xs[NPB * RS];

    const int tid  = threadIdx.x;
    const int base = blockIdx.x * NPB;
    const int wave = tid >> 6;
    const int lane = tid & 63;

    if (WSTYLE == 0) {
        // stage weights (4096 floats each; 256 threads x 4 float4)
        const float4* wl4 = (const float4*)Wl;
        const float4* wr4 = (const float4*)Wr;
        float4* wls4 = (float4*)WlS;
        float4* wrs4 = (float4*)WrS;
        #pragma unroll
        for (int i = 0; i < 4; ++i) {
            wls4[tid + i * 256] = wl4[tid + i * 256];
            wrs4[tid + i * 256] = wr4[tid + i * 256];
        }
    }
    // stage agg rows + self rows (+input affine on self)
    {
        const int r0 = tid >> 4;          // 0..15
        const int c4 = (tid & 15) * 4;    // 0..60
        #pragma unroll
        for (int pp = 0; pp < 4; ++pp) {
            int row = pp * 16 + r0;
            int gn  = base + row;
            float4 va = make_float4(0.f, 0.f, 0.f, 0.f);
            float4 vx = make_float4(0.f, 0.f, 0.f, 0.f);
            if (gn < N) {
                va = *(const float4*)&agg[(size_t)gn * D + c4];
                vx = *(const float4*)&in[(size_t)gn * D + c4];
            }
            if (MODE != 0) {
                vx.x = vx.x * aff_a[c4 + 0] + aff_c[c4 + 0];
                vx.y = vx.y * aff_a[c4 + 1] + aff_c[c4 + 1];
                vx.z = vx.z * aff_a[c4 + 2] + aff_c[c4 + 2];
                vx.w = vx.w * aff_a[c4 + 3] + aff_c[c4 + 3];
            }
            *(float4*)&aggs[row * RS + c4] = va;
            *(float4*)&xs[row * RS + c4]   = vx;
        }
    }
    __syncthreads();

    // matmul: wave w computes features [w*16, w*16+16) for all 64 nodes; lane = node
    float acc[16];
    #pragma unroll
    for (int jj = 0; jj < 16; ++jj) acc[jj] = 0.f;
    const int jg  = wave * 16;
    const int jgu = __builtin_amdgcn_readfirstlane(jg);  // force SGPR-uniform
    const int n   = lane;
    for (int k = 0; k < D; k += 4) {
        float4 a4 = *(const float4*)&aggs[n * RS + k];
        float4 x4 = *(const float4*)&xs[n * RS + k];
        const float* ap = (const float*)&a4;
        const float* xp = (const float*)&x4;
        #pragma unroll
        for (int kk = 0; kk < 4; ++kk) {
            const float avv = ap[kk];
            const float xvv = xp[kk];
            const float* wlr = (WSTYLE == 0) ? &WlS[(k + kk) * D + jg]
                                             : &Wl[(size_t)(k + kk) * D + jgu];
            const float* wrr = (WSTYLE == 0) ? &WrS[(k + kk) * D + jg]
                                             : &Wr[(size_t)(k + kk) * D + jgu];
            #pragma unroll
            for (int jj = 0; jj < 16; ++jj) {
                acc[jj] += avv * wlr[jj];
                acc[jj] += xvv * wrr[jj];
            }
        }
    }
    __syncthreads();  // all waves done reading aggs/xs

    if (MODE != 2) {
        float hv[16];
        #pragma unroll
        for (int jj = 0; jj < 16; ++jj) {
            float v = acc[jj] + bl[jg + jj];
            hv[jj] = lrelu(v);
        }
        // transpose through LDS (reuse aggs) for coalesced writeback
        #pragma unroll
        for (int q = 0; q < 4; ++q) {
            float4 v4 = make_float4(hv[q * 4 + 0], hv[q * 4 + 1], hv[q * 4 + 2], hv[q * 4 + 3]);
            *(float4*)&aggs[n * RS + jg + q * 4] = v4;
        }
        __syncthreads();
        {
            const int r0 = tid >> 4;
            const int c4 = (tid & 15) * 4;
            #pragma unroll
            for (int pp = 0; pp < 4; ++pp) {
                int row = pp * 16 + r0;
                int gn  = base + row;
                if (gn < N)
                    *(float4*)&hout[(size_t)gn * D + c4] = *(const float4*)&aggs[row * RS + c4];
            }
        }
        // BN partial stats: per-wave shuffle reduce, non-atomic per-block store
        bool valid = (base + n) < N;
        #pragma unroll
        for (int jj = 0; jj < 16; ++jj) {
            float s1 = valid ? hv[jj] : 0.f;
            float s2 = s1 * s1;
            #pragma unroll
            for (int o = 32; o > 0; o >>= 1) {
                s1 += __shfl_xor(s1, o, 64);
                s2 += __shfl_xor(s2, o, 64);
            }
            if (lane == 0) {
                blkstats[(size_t)blockIdx.x * 128 + jg + jj]      = s1;
                blkstats[(size_t)blockIdx.x * 128 + 64 + jg + jj] = s2;
            }
        }
    } else {
        // fused FC head: out[n] = lrelu(h2) . wfc + bfc
        float s = 0.f;
        #pragma unroll
        for (int jj = 0; jj < 16; ++jj) {
            float v = acc[jj] + bl[jg + jj];
            s += lrelu(v) * wfc[jg + jj];
        }
        aggs[wave * 64 + n] = s;   // scratch reuse, post-barrier
        __syncthreads();
        if (wave == 0) {
            int gn = base + lane;
            if (gn < N)
                out[gn] = aggs[lane] + aggs[64 + lane] + aggs[128 + lane] + aggs[192 + lane] + bfc[0];
        }
    }
}

// ---------------- launch ----------------

extern "C" void kernel_launch(void* const* d_in, const int* in_sizes, int n_in,
                              void* d_out, int out_size, void* d_ws, size_t ws_size,
                              hipStream_t stream) {
    const float* x   = (const float*)d_in[0];
    const int*   ei  = (const int*)d_in[1];
    const float* W0l = (const float*)d_in[2];
    const float* b0  = (const float*)d_in[3];
    const float* W0r = (const float*)d_in[4];
    const float* g0  = (const float*)d_in[5];
    const float* be0 = (const float*)d_in[6];
    const float* W1l = (const float*)d_in[7];
    const float* b1  = (const float*)d_in[8];
    const float* W1r = (const float*)d_in[9];
    const float* g1  = (const float*)d_in[10];
    const float* be1 = (const float*)d_in[11];
    const float* W2l = (const float*)d_in[12];
    const float* b2  = (const float*)d_in[13];
    const float* W2r = (const float*)d_in[14];
    const float* Wfc = (const float*)d_in[15];
    const float* bfc = (const float*)d_in[16];
    float* out = (float*)d_out;

    const int N = in_sizes[0] / D;
    const int E = in_sizes[1] / 2;
    const int* src = ei;
    const int* dst = ei + E;

    const int lbl = (N + NPB - 1) / NPB;

    char* p = (char*)d_ws;
    auto carve = [&](size_t bytes) {
        char* r = p;
        p += (bytes + 255) & ~(size_t)255;
        return r;
    };
    int*   cnt      = (int*)carve((size_t)2 * N * 4);     // cnt + cursor contiguous
    int*   cursor   = cnt + N;
    int*   offsets  = (int*)carve((size_t)(N + 1) * 4);
    int*   psum     = (int*)carve(1024 * 4);
    int*   col      = (int*)carve((size_t)E * 4);
    float* blkstats = (float*)carve((size_t)lbl * 128 * 4);
    float* partial  = (float*)carve((size_t)R1B * 128 * 4);
    float* aff      = (float*)carve(256 * 4);             // a0,c0,a1,c1
    float* h0       = (float*)carve((size_t)N * D * 4);
    float* h1       = (float*)carve((size_t)N * D * 4);
    float* aggbuf   = (float*)carve((size_t)N * D * 4);

    hipMemsetAsync(cnt, 0, (size_t)2 * N * 4, stream);

    const int ebl = (E + 255) / 256;
    const int nbl = (N + 255) / 256;

    count_kernel<<<ebl, 256, 0, stream>>>(dst, E, cnt);
    scan1_kernel<<<nbl, 256, 0, stream>>>(cnt, N, psum);
    scan2_kernel<<<1, 1024, 0, stream>>>(psum, nbl);
    scan3_kernel<<<nbl, 256, 0, stream>>>(cnt, psum, N, E, offsets);
    fill_kernel<<<ebl, 256, 0, stream>>>(src, dst, E, offsets, cursor, col);

    const int abl = (N + 3) / 4;          // 4 nodes (waves) per block
    const float invN = 1.f / (float)N;

    // layer 0 (WSTYLE 0 = LDS-staged weights, round-13 proven)
    agg_kernel<0><<<abl, 256, 0, stream>>>(x, offsets, col, nullptr, nullptr, aggbuf, N);
    layer_kernel<0, 0><<<lbl, 256, 0, stream>>>(x, aggbuf, nullptr, nullptr,
                                                W0l, b0, W0r, h0, blkstats,
                                                nullptr, nullptr, nullptr, N);
    reduce1_kernel<<<R1B, 256, 0, stream>>>(blkstats, lbl, partial);
    reduce2_affine_kernel<<<1, 256, 0, stream>>>(partial, g0, be0, aff + 0, aff + 64, invN);
    // layer 1 (WSTYLE 1 = scalar-cache weights via readfirstlane — A/B probe)
    agg_kernel<1><<<abl, 256, 0, stream>>>(h0, offsets, col, aff + 0, aff + 64, aggbuf, N);
    layer_kernel<1, 1><<<lbl, 256, 0, stream>>>(h0, aggbuf, aff + 0, aff + 64,
                                                W1l, b1, W1r, h1, blkstats,
                                                nullptr, nullptr, nullptr, N);
    reduce1_kernel<<<R1B, 256, 0, stream>>>(blkstats, lbl, partial);
    reduce2_affine_kernel<<<1, 256, 0, stream>>>(partial, g1, be1, aff + 128, aff + 192, invN);
    // layer 2 + FC head (WSTYLE 0)
    agg_kernel<1><<<abl, 256, 0, stream>>>(h1, offsets, col, aff + 128, aff + 192, aggbuf, N);
    layer_kernel<2, 0><<<lbl, 256, 0, stream>>>(h1, aggbuf, aff + 128, aff + 192,
                                                W2l, b2, W2r, nullptr, nullptr,
                                                Wfc, bfc, out, N);
}

// Round 16
// 526.113 us; speedup vs baseline: 1.3631x; 1.0355x over previous
//
#include <hip/hip_runtime.h>

#define D 64
#define NPB 64      // nodes per block in layer kernel
#define RS 68       // padded LDS row stride (floats)
#define EPSV 1e-5f
#define SLOPE 0.01f
#define R1B 64      // blocks in stage-1 stats reduce

__device__ __forceinline__ float lrelu(float v) { return v > 0.f ? v : SLOPE * v; }

// ---------------- CSR build ----------------

__global__ void count_kernel(const int* __restrict__ dst, int E, int* __restrict__ cnt) {
    int i = blockIdx.x * 256 + threadIdx.x;
    if (i < E) atomicAdd(&cnt[dst[i]], 1);
}

__global__ void scan1_kernel(const int* __restrict__ cnt, int N, int* __restrict__ psum) {
    __shared__ int sd[256];
    int t = threadIdx.x;
    int i = blockIdx.x * 256 + t;
    sd[t] = (i < N) ? cnt[i] : 0;
    __syncthreads();
    for (int o = 128; o > 0; o >>= 1) {
        if (t < o) sd[t] += sd[t + o];
        __syncthreads();
    }
    if (t == 0) psum[blockIdx.x] = sd[0];
}

__global__ void scan2_kernel(int* __restrict__ psum, int nb) {
    __shared__ int sd[1024];
    int t = threadIdx.x;
    int v = (t < nb) ? psum[t] : 0;
    int x = v;
    sd[t] = x;
    __syncthreads();
    for (int o = 1; o < 1024; o <<= 1) {
        int y = (t >= o) ? sd[t - o] : 0;
        __syncthreads();
        x += y;
        sd[t] = x;
        __syncthreads();
    }
    if (t < nb) psum[t] = x - v;  // exclusive
}

__global__ void scan3_kernel(const int* __restrict__ cnt, const int* __restrict__ psum,
                             int N, int E, int* __restrict__ offsets) {
    __shared__ int sd[256];
    int t = threadIdx.x;
    int i = blockIdx.x * 256 + t;
    int v = (i < N) ? cnt[i] : 0;
    int x = v;
    sd[t] = x;
    __syncthreads();
    for (int o = 1; o < 256; o <<= 1) {
        int y = (t >= o) ? sd[t - o] : 0;
        __syncthreads();
        x += y;
        sd[t] = x;
        __syncthreads();
    }
    if (i < N) offsets[i] = psum[blockIdx.x] + x - v;  // exclusive global
    if (i == 0) offsets[N] = E;
}

__global__ void fill_kernel(const int* __restrict__ src, const int* __restrict__ dst, int E,
                            const int* __restrict__ offsets, int* __restrict__ cursor,
                            int* __restrict__ col) {
    int i = blockIdx.x * 256 + threadIdx.x;
    if (i < E) {
        int d = dst[i];
        int p = atomicAdd(&cursor[d], 1);
        col[offsets[d] + p] = src[i];
    }
}

// ---------------- BN stats two-stage parallel reduce ----------------

__global__ void reduce1_kernel(const float* __restrict__ blkstats, int B,
                               float* __restrict__ partial) {
    __shared__ float4 sd[256];
    const int t    = threadIdx.x;
    const int c4   = t & 31;   // float4 column (32 x 4 = 128 floats)
    const int rg   = t >> 5;   // rowgroup 0..7
    float4 acc = make_float4(0.f, 0.f, 0.f, 0.f);
    for (int i = blockIdx.x * 8 + rg; i < B; i += R1B * 8) {
        float4 v = *(const float4*)&blkstats[(size_t)i * 128 + c4 * 4];
        acc.x += v.x; acc.y += v.y; acc.z += v.z; acc.w += v.w;
    }
    sd[t] = acc;
    __syncthreads();
    #pragma unroll
    for (int o = 4; o > 0; o >>= 1) {
        if (rg < o) {
            float4 a = sd[rg * 32 + c4];
            float4 b = sd[(rg + o) * 32 + c4];
            a.x += b.x; a.y += b.y; a.z += b.z; a.w += b.w;
            sd[rg * 32 + c4] = a;
        }
        __syncthreads();
    }
    if (t < 32)
        *(float4*)&partial[(size_t)blockIdx.x * 128 + c4 * 4] = sd[c4];
}

__global__ void reduce2_affine_kernel(const float* __restrict__ partial,
                                      const float* __restrict__ g, const float* __restrict__ b,
                                      float* __restrict__ a, float* __restrict__ c, float invN) {
    __shared__ float sd[2][128];
    const int t    = threadIdx.x;   // 256
    const int f    = t & 127;
    const int half = t >> 7;
    float s = 0.f;
    for (int i = half; i < R1B; i += 2)
        s += partial[(size_t)i * 128 + f];
    sd[half][f] = s;
    __syncthreads();
    if (t < 64) {
        float su = sd[0][t]      + sd[1][t];
        float sq = sd[0][64 + t] + sd[1][64 + t];
        float mu  = su * invN;
        float var = sq * invN - mu * mu;
        float aj  = g[t] * rsqrtf(var + EPSV);
        a[t] = aj;
        c[t] = b[t] - mu * aj;
    }
}

// ---------------- gather-mean kernel: one wave per node ----------------

template <int AFF>
__global__ __launch_bounds__(256, 8)
void agg_kernel(const float* __restrict__ in,
                const int* __restrict__ offsets,
                const int* __restrict__ col,
                const float* __restrict__ aff_a,
                const float* __restrict__ aff_c,
                float* __restrict__ aggout,
                int N)
{
    const int node = blockIdx.x * 4 + (threadIdx.x >> 6);
    const int lane = threadIdx.x & 63;
    if (node >= N) return;

    const int beg = offsets[node];
    const int end = offsets[node + 1];
    const int deg = end - beg;

    float a0 = 0.f, a1 = 0.f, a2 = 0.f, a3 = 0.f;
    float a4 = 0.f, a5 = 0.f, a6 = 0.f, a7 = 0.f;

    for (int cb = beg; cb < end; cb += 64) {
        const int nn = min(64, end - cb);
        const int cidx = (lane < nn) ? col[cb + lane] : 0;
        int j = 0;
        for (; j + 8 <= nn; j += 8) {
            const int c0 = __shfl(cidx, j + 0);
            const int c1 = __shfl(cidx, j + 1);
            const int c2 = __shfl(cidx, j + 2);
            const int c3 = __shfl(cidx, j + 3);
            const int c4 = __shfl(cidx, j + 4);
            const int c5 = __shfl(cidx, j + 5);
            const int c6 = __shfl(cidx, j + 6);
            const int c7 = __shfl(cidx, j + 7);
            a0 += in[(size_t)c0 * D + lane];
            a1 += in[(size_t)c1 * D + lane];
            a2 += in[(size_t)c2 * D + lane];
            a3 += in[(size_t)c3 * D + lane];
            a4 += in[(size_t)c4 * D + lane];
            a5 += in[(size_t)c5 * D + lane];
            a6 += in[(size_t)c6 * D + lane];
            a7 += in[(size_t)c7 * D + lane];
        }
        for (; j + 4 <= nn; j += 4) {
            const int c0 = __shfl(cidx, j + 0);
            const int c1 = __shfl(cidx, j + 1);
            const int c2 = __shfl(cidx, j + 2);
            const int c3 = __shfl(cidx, j + 3);
            a0 += in[(size_t)c0 * D + lane];
            a1 += in[(size_t)c1 * D + lane];
            a2 += in[(size_t)c2 * D + lane];
            a3 += in[(size_t)c3 * D + lane];
        }
        for (; j < nn; ++j) {
            const int c = __shfl(cidx, j);
            a0 += in[(size_t)c * D + lane];
        }
    }

    float agg = 0.f;
    if (deg > 0) {
        agg = (((a0 + a1) + (a2 + a3)) + ((a4 + a5) + (a6 + a7))) / (float)deg;
        if (AFF) agg = agg * aff_a[lane] + aff_c[lane];
    }
    aggout[(size_t)node * D + lane] = agg;
}

// ---------------- fused dense layer ----------------
// LDS-staged weights (round-13 proven; round-15 A/B showed scalar-weight path
// is neutral/worse). Round-16 change: weight reads in the inner loop are
// explicit float4 (ds_read_b128 broadcasts) instead of 16 scalar ds_read_b32
// per matrix per k-substep -> 4x fewer LDS instructions on the weight path,
// which the cycle model says dominated the ~65us layer time.

template <int MODE>
__global__ __launch_bounds__(256, 2)
void layer_kernel(const float* __restrict__ in,
                  const float* __restrict__ agg,
                  const float* __restrict__ aff_a,
                  const float* __restrict__ aff_c,
                  const float* __restrict__ Wl,
                  const float* __restrict__ bl,
                  const float* __restrict__ Wr,
                  float* __restrict__ hout,
                  float* __restrict__ blkstats,
                  const float* __restrict__ wfc,
                  const float* __restrict__ bfc,
                  float* __restrict__ out,
                  int N)
{
    __shared__ float WlS[D * D];
    __shared__ float WrS[D * D];
    __shared__ float aggs[NPB * RS];
    __shared__ float xs[NPB * RS];

    const int tid  = threadIdx.x;
    const int base = blockIdx.x * NPB;
    const int wave = tid >> 6;
    const int lane = tid & 63;

    // stage weights (4096 floats each; 256 threads x 4 float4)
    {
        const float4* wl4 = (const float4*)Wl;
        const float4* wr4 = (const float4*)Wr;
        float4* wls4 = (float4*)WlS;
        float4* wrs4 = (float4*)WrS;
        #pragma unroll
        for (int i = 0; i < 4; ++i) {
            wls4[tid + i * 256] = wl4[tid + i * 256];
            wrs4[tid + i * 256] = wr4[tid + i * 256];
        }
    }
    // stage agg rows + self rows (+input affine on self)
    {
        const int r0 = tid >> 4;          // 0..15
        const int c4 = (tid & 15) * 4;    // 0..60
        #pragma unroll
        for (int pp = 0; pp < 4; ++pp) {
            int row = pp * 16 + r0;
            int gn  = base + row;
            float4 va = make_float4(0.f, 0.f, 0.f, 0.f);
            float4 vx = make_float4(0.f, 0.f, 0.f, 0.f);
            if (gn < N) {
                va = *(const float4*)&agg[(size_t)gn * D + c4];
                vx = *(const float4*)&in[(size_t)gn * D + c4];
            }
            if (MODE != 0) {
                vx.x = vx.x * aff_a[c4 + 0] + aff_c[c4 + 0];
                vx.y = vx.y * aff_a[c4 + 1] + aff_c[c4 + 1];
                vx.z = vx.z * aff_a[c4 + 2] + aff_c[c4 + 2];
                vx.w = vx.w * aff_a[c4 + 3] + aff_c[c4 + 3];
            }
            *(float4*)&aggs[row * RS + c4] = va;
            *(float4*)&xs[row * RS + c4]   = vx;
        }
    }
    __syncthreads();

    // matmul: wave w computes features [w*16, w*16+16) for all 64 nodes; lane = node
    float acc[16];
    #pragma unroll
    for (int jj = 0; jj < 16; ++jj) acc[jj] = 0.f;
    const int jg = wave * 16;
    const int n  = lane;
    for (int k = 0; k < D; k += 4) {
        float4 a4 = *(const float4*)&aggs[n * RS + k];
        float4 x4 = *(const float4*)&xs[n * RS + k];
        const float* ap = (const float*)&a4;
        const float* xp = (const float*)&x4;
        #pragma unroll
        for (int kk = 0; kk < 4; ++kk) {
            const float avv = ap[kk];
            const float xvv = xp[kk];
            const float4* wl4p = (const float4*)&WlS[(k + kk) * D + jg];
            const float4* wr4p = (const float4*)&WrS[(k + kk) * D + jg];
            #pragma unroll
            for (int q = 0; q < 4; ++q) {
                float4 wl = wl4p[q];
                float4 wr = wr4p[q];
                acc[q * 4 + 0] += avv * wl.x;
                acc[q * 4 + 0] += xvv * wr.x;
                acc[q * 4 + 1] += avv * wl.y;
                acc[q * 4 + 1] += xvv * wr.y;
                acc[q * 4 + 2] += avv * wl.z;
                acc[q * 4 + 2] += xvv * wr.z;
                acc[q * 4 + 3] += avv * wl.w;
                acc[q * 4 + 3] += xvv * wr.w;
            }
        }
    }
    __syncthreads();  // all waves done reading aggs/xs

    if (MODE != 2) {
        float hv[16];
        #pragma unroll
        for (int jj = 0; jj < 16; ++jj) {
            float v = acc[jj] + bl[jg + jj];
            hv[jj] = lrelu(v);
        }
        // transpose through LDS (reuse aggs) for coalesced writeback
        #pragma unroll
        for (int q = 0; q < 4; ++q) {
            float4 v4 = make_float4(hv[q * 4 + 0], hv[q * 4 + 1], hv[q * 4 + 2], hv[q * 4 + 3]);
            *(float4*)&aggs[n * RS + jg + q * 4] = v4;
        }
        __syncthreads();
        {
            const int r0 = tid >> 4;
            const int c4 = (tid & 15) * 4;
            #pragma unroll
            for (int pp = 0; pp < 4; ++pp) {
                int row = pp * 16 + r0;
                int gn  = base + row;
                if (gn < N)
                    *(float4*)&hout[(size_t)gn * D + c4] = *(const float4*)&aggs[row * RS + c4];
            }
        }
        // BN partial stats: per-wave shuffle reduce, non-atomic per-block store
        bool valid = (base + n) < N;
        #pragma unroll
        for (int jj = 0; jj < 16; ++jj) {
            float s1 = valid ? hv[jj] : 0.f;
            float s2 = s1 * s1;
            #pragma unroll
            for (int o = 32; o > 0; o >>= 1) {
                s1 += __shfl_xor(s1, o, 64);
                s2 += __shfl_xor(s2, o, 64);
            }
            if (lane == 0) {
                blkstats[(size_t)blockIdx.x * 128 + jg + jj]      = s1;
                blkstats[(size_t)blockIdx.x * 128 + 64 + jg + jj] = s2;
            }
        }
    } else {
        // fused FC head: out[n] = lrelu(h2) . wfc + bfc
        float s = 0.f;
        #pragma unroll
        for (int jj = 0; jj < 16; ++jj) {
            float v = acc[jj] + bl[jg + jj];
            s += lrelu(v) * wfc[jg + jj];
        }
        aggs[wave * 64 + n] = s;   // scratch reuse, post-barrier
        __syncthreads();
        if (wave == 0) {
            int gn = base + lane;
            if (gn < N)
                out[gn] = aggs[lane] + aggs[64 + lane] + aggs[128 + lane] + aggs[192 + lane] + bfc[0];
        }
    }
}

// ---------------- launch ----------------

extern "C" void kernel_launch(void* const* d_in, const int* in_sizes, int n_in,
                              void* d_out, int out_size, void* d_ws, size_t ws_size,
                              hipStream_t stream) {
    const float* x   = (const float*)d_in[0];
    const int*   ei  = (const int*)d_in[1];
    const float* W0l = (const float*)d_in[2];
    const float* b0  = (const float*)d_in[3];
    const float* W0r = (const float*)d_in[4];
    const float* g0  = (const float*)d_in[5];
    const float* be0 = (const float*)d_in[6];
    const float* W1l = (const float*)d_in[7];
    const float* b1  = (const float*)d_in[8];
    const float* W1r = (const float*)d_in[9];
    const float* g1  = (const float*)d_in[10];
    const float* be1 = (const float*)d_in[11];
    const float* W2l = (const float*)d_in[12];
    const float* b2  = (const float*)d_in[13];
    const float* W2r = (const float*)d_in[14];
    const float* Wfc = (const float*)d_in[15];
    const float* bfc = (const float*)d_in[16];
    float* out = (float*)d_out;

    const int N = in_sizes[0] / D;
    const int E = in_sizes[1] / 2;
    const int* src = ei;
    const int* dst = ei + E;

    const int lbl = (N + NPB - 1) / NPB;

    char* p = (char*)d_ws;
    auto carve = [&](size_t bytes) {
        char* r = p;
        p += (bytes + 255) & ~(size_t)255;
        return r;
    };
    int*   cnt      = (int*)carve((size_t)2 * N * 4);     // cnt + cursor contiguous
    int*   cursor   = cnt + N;
    int*   offsets  = (int*)carve((size_t)(N + 1) * 4);
    int*   psum     = (int*)carve(1024 * 4);
    int*   col      = (int*)carve((size_t)E * 4);
    float* blkstats = (float*)carve((size_t)lbl * 128 * 4);
    float* partial  = (float*)carve((size_t)R1B * 128 * 4);
    float* aff      = (float*)carve(256 * 4);             // a0,c0,a1,c1
    float* h0       = (float*)carve((size_t)N * D * 4);
    float* h1       = (float*)carve((size_t)N * D * 4);
    float* aggbuf   = (float*)carve((size_t)N * D * 4);

    hipMemsetAsync(cnt, 0, (size_t)2 * N * 4, stream);

    const int ebl = (E + 255) / 256;
    const int nbl = (N + 255) / 256;

    count_kernel<<<ebl, 256, 0, stream>>>(dst, E, cnt);
    scan1_kernel<<<nbl, 256, 0, stream>>>(cnt, N, psum);
    scan2_kernel<<<1, 1024, 0, stream>>>(psum, nbl);
    scan3_kernel<<<nbl, 256, 0, stream>>>(cnt, psum, N, E, offsets);
    fill_kernel<<<ebl, 256, 0, stream>>>(src, dst, E, offsets, cursor, col);

    const int abl = (N + 3) / 4;          // 4 nodes (waves) per block
    const float invN = 1.f / (float)N;

    // layer 0
    agg_kernel<0><<<abl, 256, 0, stream>>>(x, offsets, col, nullptr, nullptr, aggbuf, N);
    layer_kernel<0><<<lbl, 256, 0, stream>>>(x, aggbuf, nullptr, nullptr,
                                             W0l, b0, W0r, h0, blkstats,
                                             nullptr, nullptr, nullptr, N);
    reduce1_kernel<<<R1B, 256, 0, stream>>>(blkstats, lbl, partial);
    reduce2_affine_kernel<<<1, 256, 0, stream>>>(partial, g0, be0, aff + 0, aff + 64, invN);
    // layer 1
    agg_kernel<1><<<abl, 256, 0, stream>>>(h0, offsets, col, aff + 0, aff + 64, aggbuf, N);
    layer_kernel<1><<<lbl, 256, 0, stream>>>(h0, aggbuf, aff + 0, aff + 64,
                                             W1l, b1, W1r, h1, blkstats,
                                             nullptr, nullptr, nullptr, N);
    reduce1_kernel<<<R1B, 256, 0, stream>>>(blkstats, lbl, partial);
    reduce2_affine_kernel<<<1, 256, 0, stream>>>(partial, g1, be1, aff + 128, aff + 192, invN);
    // layer 2 + FC head
    agg_kernel<1><<<abl, 256, 0, stream>>>(h1, offsets, col, aff + 128, aff + 192, aggbuf, N);
    layer_kernel<2><<<lbl, 256, 0, stream>>>(h1, aggbuf, aff + 128, aff + 192,
                                             W2l, b2, W2r, nullptr, nullptr,
                                             Wfc, bfc, out, N);
}